// Round 1
// baseline (564.292 us; speedup 1.0000x reference)
//
#include <hip/hip_runtime.h>
#include <hip/hip_bf16.h>
#include <stdint.h>

// ---- types ----
typedef __bf16 bf16x8 __attribute__((ext_vector_type(8)));
typedef float  f32x4  __attribute__((ext_vector_type(4)));

#define MFMA16(a,b,c) __builtin_amdgcn_mfma_f32_16x16x32_bf16((a),(b),(c),0,0,0)

__device__ __forceinline__ void gld16(const void* g, void* l) {
    __builtin_amdgcn_global_load_lds((__attribute__((address_space(1))) void*)(g),
                                     (__attribute__((address_space(3))) void*)(l), 16, 0, 0);
}

// ---------------------------------------------------------------- cast f32->bf16
__global__ __launch_bounds__(256) void cast_bf16_kernel(const float* __restrict__ x,
                                                        __hip_bfloat16* __restrict__ y, int n4) {
    int i = blockIdx.x * 256 + threadIdx.x;
    if (i >= n4) return;
    float4 v = ((const float4*)x)[i];
    union { ushort4 u; __hip_bfloat16 b[4]; } c;
    c.b[0] = __float2bfloat16(v.x);
    c.b[1] = __float2bfloat16(v.y);
    c.b[2] = __float2bfloat16(v.z);
    c.b[3] = __float2bfloat16(v.w);
    ((ushort4*)y)[i] = c.u;
}

// ---------------------------------------------------------- W [K=1024,N=1024] f32 -> Wt bf16 [N,K]
__global__ __launch_bounds__(256) void transpose_w_kernel(const float* __restrict__ W,
                                                          __hip_bfloat16* __restrict__ Wt) {
    __shared__ float tile[32][33];
    int n0 = blockIdx.x * 32, k0 = blockIdx.y * 32;
    int tx = threadIdx.x & 31, ty = threadIdx.x >> 5;
    for (int i = ty; i < 32; i += 8)
        tile[i][tx] = W[(size_t)(k0 + i) * 1024 + n0 + tx];
    __syncthreads();
    for (int i = ty; i < 32; i += 8)
        Wt[(size_t)(n0 + i) * 1024 + k0 + tx] = __float2bfloat16(tile[tx][i]);
}

// ------------------------------------------------- vp [8192,1024] bf16 -> vt [64bh][64d][2048s]
__global__ __launch_bounds__(256) void transpose_v_kernel(const __hip_bfloat16* __restrict__ vp,
                                                          __hip_bfloat16* __restrict__ vt) {
    __shared__ __hip_bfloat16 tile[64][65];
    int s0 = blockIdx.x * 64;
    int bh = blockIdx.y; int bb = bh >> 4, h = bh & 15;
    int tx = threadIdx.x & 63, ty = threadIdx.x >> 6;
    for (int i = ty; i < 64; i += 4)
        tile[i][tx] = vp[(size_t)(bb * 2048 + s0 + i) * 1024 + h * 64 + tx];
    __syncthreads();
    for (int i = ty; i < 64; i += 4)
        vt[((size_t)bh * 64 + i) * 2048 + s0 + tx] = tile[tx][i];
}

// --------------------------------------------------------------- GEMM C = A @ Bt^T + bias
// A bf16 [M,K] row-major, Bt bf16 [N,K] row-major (i.e. B^T), bias f32 [N]
// MODE 0: store bf16 C.  MODE 1: store f32 C + bf16 residual.
template <int MODE>
__global__ __launch_bounds__(256) void gemm_bt_kernel(const __hip_bfloat16* __restrict__ A,
                                                      const __hip_bfloat16* __restrict__ Bt,
                                                      const float* __restrict__ bias,
                                                      const __hip_bfloat16* __restrict__ res,
                                                      __hip_bfloat16* __restrict__ Cb,
                                                      float* __restrict__ Cf,
                                                      int M, int N, int K) {
    __shared__ __attribute__((aligned(16))) __hip_bfloat16 As[128 * 32];
    __shared__ __attribute__((aligned(16))) __hip_bfloat16 Bs[128 * 32];
    const int t = threadIdx.x;
    const int lane = t & 63, w = t >> 6;
    const int m16 = lane & 15, quad = lane >> 4;
    const int wm = w >> 1, wn = w & 1;
    const int bm = blockIdx.x, bn = blockIdx.y;

    const __hip_bfloat16* Ag = A + (size_t)(bm * 128 + (t >> 2)) * K + (t & 3) * 8;
    const __hip_bfloat16* Bg = Bt + (size_t)(bn * 128 + (t >> 2)) * K + (t & 3) * 8;

    f32x4 acc[4][4] = {};

    for (int k0 = 0; k0 < K; k0 += 32) {
        gld16(Ag + k0,             &As[t * 8]);
        gld16(Ag + (size_t)64 * K + k0, &As[2048 + t * 8]);
        gld16(Bg + k0,             &Bs[t * 8]);
        gld16(Bg + (size_t)64 * K + k0, &Bs[2048 + t * 8]);
        __syncthreads();
        bf16x8 af[4], bfr[4];
#pragma unroll
        for (int i = 0; i < 4; ++i) {
            af[i]  = *(const bf16x8*)&As[(wm * 64 + i * 16 + m16) * 32 + quad * 8];
            bfr[i] = *(const bf16x8*)&Bs[(wn * 64 + i * 16 + m16) * 32 + quad * 8];
        }
#pragma unroll
        for (int i = 0; i < 4; ++i)
#pragma unroll
            for (int j = 0; j < 4; ++j)
                acc[i][j] = MFMA16(af[i], bfr[j], acc[i][j]);
        __syncthreads();
    }

#pragma unroll
    for (int j = 0; j < 4; ++j) {
        int col = bn * 128 + wn * 64 + j * 16 + m16;
        float bv = bias[col];
#pragma unroll
        for (int i = 0; i < 4; ++i) {
            int row0 = bm * 128 + wm * 64 + i * 16 + quad * 4;
#pragma unroll
            for (int r = 0; r < 4; ++r) {
                size_t idx = (size_t)(row0 + r) * N + col;
                float v = acc[i][j][r] + bv;
                if (MODE == 0) Cb[idx] = __float2bfloat16(v);
                else           Cf[idx] = v + __bfloat162float(res[idx]);
            }
        }
    }
}

// --------------------------------------------------------------- flash attention
// qp,kp bf16 [8192, 1024] (token-major, head h at cols h*64..); vt bf16 [64bh][64d][2048s]
// out ctx bf16 [8192, 1024]
__global__ __launch_bounds__(256) void attn_kernel(const __hip_bfloat16* __restrict__ qp,
                                                   const __hip_bfloat16* __restrict__ kp,
                                                   const __hip_bfloat16* __restrict__ vt,
                                                   __hip_bfloat16* __restrict__ ctx) {
    __shared__ __attribute__((aligned(16))) __hip_bfloat16 Qs[128 * 64];   // 16 KB
    __shared__ __attribute__((aligned(16))) __hip_bfloat16 Ks[128 * 64];   // 16 KB
    __shared__ __attribute__((aligned(16))) __hip_bfloat16 Vs[64 * 128];   // 16 KB  (d-major)
    __shared__ __attribute__((aligned(16))) __hip_bfloat16 Ps[4 * 32 * 64];// 16 KB  (per-wave 32x64)

    const int t = threadIdx.x;
    const int lane = t & 63, w = t >> 6;
    const int m16 = lane & 15, quad = lane >> 4;
    const int qtile = blockIdx.x;          // 0..15
    const int bh = blockIdx.y;             // 0..63
    const int b = bh >> 4, h = bh & 15;
    const float scale = 0.125f;            // 1/sqrt(64)

    // ---- stage Q tile [128 rows][64] ----
#pragma unroll
    for (int i = 0; i < 4; ++i) {
        int row = (t >> 3) + i * 32;
        gld16(qp + (size_t)(b * 2048 + qtile * 128 + row) * 1024 + h * 64 + (t & 7) * 8,
              &Qs[i * 2048 + t * 8]);
    }
    __syncthreads();

    bf16x8 qf[2][2];
#pragma unroll
    for (int mi = 0; mi < 2; ++mi)
#pragma unroll
        for (int ks = 0; ks < 2; ++ks)
            qf[mi][ks] = *(const bf16x8*)&Qs[(w * 32 + mi * 16 + m16) * 64 + ks * 32 + quad * 8];

    f32x4 oacc[2][4] = {};
    float m_run[2][4], l_run[2][4];
#pragma unroll
    for (int mi = 0; mi < 2; ++mi)
#pragma unroll
        for (int r = 0; r < 4; ++r) { m_run[mi][r] = -1e30f; l_run[mi][r] = 0.f; }

    __hip_bfloat16* Pw = &Ps[w * 2048];

    for (int kt = 0; kt < 16; ++kt) {
        // stage K tile [128 keys][64]
#pragma unroll
        for (int i = 0; i < 4; ++i) {
            int key = (t >> 3) + i * 32;
            gld16(kp + (size_t)(b * 2048 + kt * 128 + key) * 1024 + h * 64 + (t & 7) * 8,
                  &Ks[i * 2048 + t * 8]);
        }
        // stage V tile (transposed: [64 d][128 keys])
#pragma unroll
        for (int i = 0; i < 4; ++i) {
            int d = (t >> 4) + i * 16;
            gld16(vt + ((size_t)bh * 64 + d) * 2048 + kt * 128 + (t & 15) * 8,
                  &Vs[i * 2048 + t * 8]);
        }
        __syncthreads();

        // S = Q K^T  (per wave: 32 q-rows x 128 keys)
        f32x4 sacc[2][8] = {};
#pragma unroll
        for (int ks = 0; ks < 2; ++ks)
#pragma unroll
            for (int nj = 0; nj < 8; ++nj) {
                bf16x8 kf = *(const bf16x8*)&Ks[(nj * 16 + m16) * 64 + ks * 32 + quad * 8];
                sacc[0][nj] = MFMA16(qf[0][ks], kf, sacc[0][nj]);
                sacc[1][nj] = MFMA16(qf[1][ks], kf, sacc[1][nj]);
            }

        // online softmax (rows: quad*4+r + mi*16 + w*32; cols: nj*16 + m16)
#pragma unroll
        for (int mi = 0; mi < 2; ++mi)
#pragma unroll
            for (int r = 0; r < 4; ++r) {
                float mx = -1e30f;
#pragma unroll
                for (int nj = 0; nj < 8; ++nj) mx = fmaxf(mx, sacc[mi][nj][r]);
                mx = fmaxf(mx, __shfl_xor(mx, 1));
                mx = fmaxf(mx, __shfl_xor(mx, 2));
                mx = fmaxf(mx, __shfl_xor(mx, 4));
                mx = fmaxf(mx, __shfl_xor(mx, 8));
                mx *= scale;
                float mnew  = fmaxf(m_run[mi][r], mx);
                float alpha = __expf(m_run[mi][r] - mnew);
                m_run[mi][r] = mnew;
                float rs = 0.f;
#pragma unroll
                for (int nj = 0; nj < 8; ++nj) {
                    float p = __expf(sacc[mi][nj][r] * scale - mnew);
                    sacc[mi][nj][r] = p;
                    rs += p;
                }
                rs += __shfl_xor(rs, 1);
                rs += __shfl_xor(rs, 2);
                rs += __shfl_xor(rs, 4);
                rs += __shfl_xor(rs, 8);
                l_run[mi][r] = l_run[mi][r] * alpha + rs;
#pragma unroll
                for (int dj = 0; dj < 4; ++dj) oacc[mi][dj][r] *= alpha;
            }

        // P (C-layout) -> per-wave LDS -> A-operand frags; PV accumulate. Two halves of 64 keys.
#pragma unroll
        for (int hf = 0; hf < 2; ++hf) {
#pragma unroll
            for (int mi = 0; mi < 2; ++mi)
#pragma unroll
                for (int nj4 = 0; nj4 < 4; ++nj4)
#pragma unroll
                    for (int r = 0; r < 4; ++r)
                        Pw[(mi * 16 + quad * 4 + r) * 64 + nj4 * 16 + m16] =
                            __float2bfloat16(sacc[mi][hf * 4 + nj4][r]);
#pragma unroll
            for (int ks = 0; ks < 2; ++ks) {
                int kg = hf * 2 + ks;
                bf16x8 vf[4];
#pragma unroll
                for (int dj = 0; dj < 4; ++dj)
                    vf[dj] = *(const bf16x8*)&Vs[(dj * 16 + m16) * 128 + kg * 32 + quad * 8];
#pragma unroll
                for (int mi = 0; mi < 2; ++mi) {
                    bf16x8 pf = *(const bf16x8*)&Pw[(mi * 16 + m16) * 64 + ks * 32 + quad * 8];
#pragma unroll
                    for (int dj = 0; dj < 4; ++dj)
                        oacc[mi][dj] = MFMA16(pf, vf[dj], oacc[mi][dj]);
                }
            }
        }
        __syncthreads();
    }

    // final O = oacc / l, store to ctx [token][h*64+d]
#pragma unroll
    for (int mi = 0; mi < 2; ++mi)
#pragma unroll
        for (int dj = 0; dj < 4; ++dj)
#pragma unroll
            for (int r = 0; r < 4; ++r) {
                int srow = qtile * 128 + w * 32 + mi * 16 + quad * 4 + r;
                size_t token = (size_t)b * 2048 + srow;
                int d = dj * 16 + m16;
                ctx[token * 1024 + h * 64 + d] =
                    __float2bfloat16(oacc[mi][dj][r] / l_run[mi][r]);
            }
}

// --------------------------------------------------------------- layernorm rows of 1024
__global__ __launch_bounds__(256) void layernorm_kernel(const float* __restrict__ x,
                                                        const float* __restrict__ gamma,
                                                        const float* __restrict__ beta,
                                                        float* __restrict__ out) {
    int row = blockIdx.x;
    int t = threadIdx.x;
    const float4* xr = (const float4*)(x + (size_t)row * 1024);
    float4 v = xr[t];
    float s  = v.x + v.y + v.z + v.w;
    float s2 = v.x * v.x + v.y * v.y + v.z * v.z + v.w * v.w;
#pragma unroll
    for (int off = 32; off > 0; off >>= 1) {
        s  += __shfl_down(s, off);
        s2 += __shfl_down(s2, off);
    }
    __shared__ float red[8];
    int w = t >> 6, lane = t & 63;
    if (lane == 0) { red[w] = s; red[4 + w] = s2; }
    __syncthreads();
    s  = red[0] + red[1] + red[2] + red[3];
    s2 = red[4] + red[5] + red[6] + red[7];
    float mu  = s * (1.f / 1024.f);
    float var = s2 * (1.f / 1024.f) - mu * mu;
    float rstd = rsqrtf(var + 1e-5f);
    float4 g  = ((const float4*)gamma)[t];
    float4 be = ((const float4*)beta)[t];
    float4 o;
    o.x = (v.x - mu) * rstd * g.x + be.x;
    o.y = (v.y - mu) * rstd * g.y + be.y;
    o.z = (v.z - mu) * rstd * g.z + be.z;
    o.w = (v.w - mu) * rstd * g.w + be.w;
    ((float4*)(out + (size_t)row * 1024))[t] = o;
}

// ----------------------------------------------------------------------------
extern "C" void kernel_launch(void* const* d_in, const int* in_sizes, int n_in,
                              void* d_out, int out_size, void* d_ws, size_t ws_size,
                              hipStream_t stream) {
    const float* q    = (const float*)d_in[0];
    const float* k    = (const float*)d_in[1];
    const float* v    = (const float*)d_in[2];
    const float* Wq   = (const float*)d_in[3];
    const float* bq   = (const float*)d_in[4];
    const float* Wk   = (const float*)d_in[5];
    const float* bk   = (const float*)d_in[6];
    const float* Wv   = (const float*)d_in[7];
    const float* bv   = (const float*)d_in[8];
    const float* Wfc  = (const float*)d_in[9];
    const float* bfc  = (const float*)d_in[10];
    const float* gamma= (const float*)d_in[11];
    const float* beta = (const float*)d_in[12];
    float* out = (float*)d_out;

    char* ws = (char*)d_ws;
    const size_t SZ  = (size_t)8192 * 1024 * 2;   // bf16 [8192,1024]
    const size_t WSZ = (size_t)1024 * 1024 * 2;   // bf16 [1024,1024]
    __hip_bfloat16* qb  = (__hip_bfloat16*)(ws + 0 * SZ);
    __hip_bfloat16* kb  = (__hip_bfloat16*)(ws + 1 * SZ);
    __hip_bfloat16* vb  = (__hip_bfloat16*)(ws + 2 * SZ);
    __hip_bfloat16* qp  = (__hip_bfloat16*)(ws + 3 * SZ);
    __hip_bfloat16* kp  = (__hip_bfloat16*)(ws + 4 * SZ);
    __hip_bfloat16* vp  = (__hip_bfloat16*)(ws + 5 * SZ);
    __hip_bfloat16* ctx = (__hip_bfloat16*)(ws + 6 * SZ);
    __hip_bfloat16* WqT = (__hip_bfloat16*)(ws + 7 * SZ);
    __hip_bfloat16* WkT = (__hip_bfloat16*)(ws + 7 * SZ + 1 * WSZ);
    __hip_bfloat16* WvT = (__hip_bfloat16*)(ws + 7 * SZ + 2 * WSZ);
    __hip_bfloat16* WfcT= (__hip_bfloat16*)(ws + 7 * SZ + 3 * WSZ);
    float*          x   = (float*)(ws + 0 * SZ);  // aliases qb+kb (both dead by then)
    __hip_bfloat16* vt  = vb;                     // aliases vb (dead after v-projection)

    const int n4 = 8192 * 1024 / 4;
    cast_bf16_kernel<<<n4 / 256, 256, 0, stream>>>(q, qb, n4);
    cast_bf16_kernel<<<n4 / 256, 256, 0, stream>>>(k, kb, n4);
    cast_bf16_kernel<<<n4 / 256, 256, 0, stream>>>(v, vb, n4);

    transpose_w_kernel<<<dim3(32, 32), 256, 0, stream>>>(Wq,  WqT);
    transpose_w_kernel<<<dim3(32, 32), 256, 0, stream>>>(Wk,  WkT);
    transpose_w_kernel<<<dim3(32, 32), 256, 0, stream>>>(Wv,  WvT);
    transpose_w_kernel<<<dim3(32, 32), 256, 0, stream>>>(Wfc, WfcT);

    gemm_bt_kernel<0><<<dim3(64, 8), 256, 0, stream>>>(qb, WqT, bq, nullptr, qp, nullptr, 8192, 1024, 1024);
    gemm_bt_kernel<0><<<dim3(64, 8), 256, 0, stream>>>(kb, WkT, bk, nullptr, kp, nullptr, 8192, 1024, 1024);
    gemm_bt_kernel<0><<<dim3(64, 8), 256, 0, stream>>>(vb, WvT, bv, nullptr, vp, nullptr, 8192, 1024, 1024);

    transpose_v_kernel<<<dim3(32, 64), 256, 0, stream>>>(vp, vt);

    attn_kernel<<<dim3(16, 64), 256, 0, stream>>>(qp, kp, vt, ctx);

    gemm_bt_kernel<1><<<dim3(64, 8), 256, 0, stream>>>(ctx, WfcT, bfc, qp, nullptr, x, 8192, 1024, 1024);

    layernorm_kernel<<<8192, 256, 0, stream>>>(x, gamma, beta, out);
}